// Round 11
// baseline (39.983 us; speedup 1.0000x reference)
//
#include <hip/hip_runtime.h>
#include <hip/hip_fp16.h>
#include <math.h>

// Radon forward, exact reference semantics (rotated-lattice bilinear gather).
//
// Round-17 changes vs round 16 (33.2 us champion; barrier-free wave tiles):
//  * r16 residual: each wave still eats an exposed wave-local vmcnt(0)
//    (~300 cyc) per subtile, 8x per wave, with only ~200 cyc of gather to
//    cover it -> waves idle >= 50%.
//  * Wave-private DOUBLE-BUFFER + COUNTED vmcnt (T3/T4, wave-local so it
//    cannot recreate r11's block-convoy failure):
//      per subtile: bbox(next) -> lgkmcnt(0)+sched_barrier (rule #18) ->
//      stage(next buf: exactly 3 gloads) -> s_waitcnt vmcnt(3) (drains
//      CURRENT buf only, next's 3 stay in flight) -> gather current.
//  * Subtiles 16j x 12i: tile 24 rows x 32 cols (span sqrt(15^2+11^2)+4
//    ~= 22.6 <= 24), 3 KB; 2 bufs x 4 waves = 24.5 KB -> 6 blocks/CU
//    = 24 waves. wi=0: 16 subtiles (i 0..191), wi=1: 15 (192..362, tail
//    masked at sub 14).
//  * Inner tap loop byte-identical to r13/r16 (packed-f16 lerp, proven).
//  * Everything else (prep canvases, epilogue, fallback) unchanged.

#define G       363
#define NT      180
#define PADB    53
#define STEP    (2.0f / 362.0f)
#define DEG2RAD 0.017453292519943295f

#define TSW     32          // tile row length (u32 cells)
#define TRW     24          // tile rows
#define TCELLS  (TRW * TSW) // 768 cells = 3 KB per buffer
#define NJB     12          // j-blocks of 32
#define NJBF    6           // fallback j-blocks of 64
#define CW      264         // canvas cols (4 guard + 256 + 4 guard)
#define CH      264         // canvas rows

#define GLOAD16(gp, lp) __builtin_amdgcn_global_load_lds(                     \
    (const __attribute__((address_space(1))) void*)(gp),                      \
    (__attribute__((address_space(3))) void*)(lp), 16, 0, 0)

// ---------------- fallback gather kernel (known-good, round 1) -------------
__global__ __launch_bounds__(256) void radon_fwd(
    const float* __restrict__ x, const int* __restrict__ theta,
    float* __restrict__ out)
{
    const int t = blockIdx.x / NJBF, jb = blockIdx.x % NJBF;
    const int jl = threadIdx.x, chunk = threadIdx.y;
    const int j = jb * 64 + jl;
    const float th = (float)theta[t] * DEG2RAD;
    const float c = cosf(th), s = sinf(th);
    const float xj = fmaf((float)j, STEP, -1.0f);
    const float s181 = s * 181.0f, c181 = c * 181.0f;
    const float bx = fmaf(c, xj, 1.0f) * 181.0f;
    const float by = fmaf(-s, xj, 1.0f) * 181.0f;
    const float* img0 = x;
    const float* img1 = x + 65536;
    float acc0 = 0.f, acc1 = 0.f;
    for (int i = chunk; i < G; i += 4) {
        const float xi = fmaf((float)i, STEP, -1.0f);
        const float ix = fmaf(s181, xi, bx);
        const float iy = fmaf(c181, xi, by);
        const float fx = floorf(ix), fy = floorf(iy);
        const int ix0 = (int)fx, iy0 = (int)fy;
        const float wx1 = ix - fx, wy1 = iy - fy;
        const float wx0 = 1.f - wx1, wy0 = 1.f - wy1;
        const int cc0 = ix0 - 53, cc1 = cc0 + 1, rr0 = iy0 - 53, rr1 = rr0 + 1;
        const float wxa = ((unsigned)cc0 < 256u) ? wx0 : 0.f;
        const float wxb = ((unsigned)cc1 < 256u) ? wx1 : 0.f;
        const float wya = ((unsigned)rr0 < 256u) ? wy0 : 0.f;
        const float wyb = ((unsigned)rr1 < 256u) ? wy1 : 0.f;
        const int c0c = min(max(cc0, 0), 255), c1c = min(max(cc1, 0), 255);
        const int r0b = min(max(rr0, 0), 255) << 8, r1b = min(max(rr1, 0), 255) << 8;
        const float w00 = wya * wxa, w01 = wya * wxb, w10 = wyb * wxa, w11 = wyb * wxb;
        acc0 = fmaf(img0[r0b + c0c], w00, acc0);
        acc0 = fmaf(img0[r0b + c1c], w01, acc0);
        acc0 = fmaf(img0[r1b + c0c], w10, acc0);
        acc0 = fmaf(img0[r1b + c1c], w11, acc0);
        acc1 = fmaf(img1[r0b + c0c], w00, acc1);
        acc1 = fmaf(img1[r0b + c1c], w01, acc1);
        acc1 = fmaf(img1[r1b + c0c], w10, acc1);
        acc1 = fmaf(img1[r1b + c1c], w11, acc1);
    }
    __shared__ float red[2][4][64];
    red[0][chunk][jl] = acc0;
    red[1][chunk][jl] = acc1;
    __syncthreads();
    if (threadIdx.y < 2 && j < G) {
        const int n = threadIdx.y;
        out[n * (G * NT) + j * NT + t] =
            red[n][0][jl] + red[n][1][jl] + red[n][2][jl] + red[n][3][jl];
    }
}

// ------------- prep: f16x2 canvases only (guarded, normal + transposed) ----
__global__ __launch_bounds__(256) void prep_k(
    const float* __restrict__ x,
    unsigned* __restrict__ xIh, unsigned* __restrict__ xTIh)
{
    const int bid = blockIdx.x;            // 0..80 (9x9 grid of 32x32)
    const int tx = threadIdx.x, ty = threadIdx.y;

    __shared__ unsigned tl[32][33];
    const int cx0 = (bid % 9) * 32, cy0 = (bid / 9) * 32;
    #pragma unroll
    for (int dy = 0; dy < 32; dy += 8) {
        const int cy = cy0 + ty + dy, cx = cx0 + tx;
        const int pr = cy - 4, pc = cx - 4;
        unsigned v = 0u;
        if ((unsigned)pr < 256u && (unsigned)pc < 256u) {
            const int p = pr * 256 + pc;
            const unsigned short a = __half_as_ushort(__float2half_rn(x[p]));
            const unsigned short b = __half_as_ushort(__float2half_rn(x[p + 65536]));
            v = (unsigned)a | ((unsigned)b << 16);
        }
        if (cy < CH && cx < CW) xIh[cy * CW + cx] = v;
        tl[ty + dy][tx] = v;
    }
    __syncthreads();
    #pragma unroll
    for (int dy = 0; dy < 32; dy += 8) {
        const int rp = cx0 + ty + dy, cp = cy0 + tx;
        if (rp < CH && cp < CW) xTIh[rp * CW + cp] = tl[tx][ty + dy];
    }
}

// ---------------- staging: 3x global_load_lds into wave-private 24x32 ------
template<bool SAFE>
__device__ __forceinline__ void stage24(char* buf_b,
    const unsigned* __restrict__ srcC, int r0p, int c0p, int lane)
{
    const int ty0 = lane >> 3;             // 0..7
    const int tx  = (lane & 7) << 2;       // 0,4,...,28 (4 cells/lane)
    #pragma unroll
    for (int u = 0; u < 3; ++u) {
        const int ty = ty0 + (u << 3);
        int idx;
        if (SAFE) {
            idx = (r0p + 4 + ty) * CW + (c0p + 4 + tx);
        } else {
            // clamp into 4-wide zero guard: OOB taps read guaranteed zeros
            const int rc = min(max(r0p + ty, -4), 256) + 4;
            const int cc = min(max(c0p + tx, -4), 256) + 4;
            idx = rc * CW + cc;
        }
        GLOAD16(srcC + idx, buf_b + (u << 10));
    }
}

// ---------------- gather inner loop (3 i-steps, packed-f16 lerp) -----------
template<bool TAIL>
__device__ __forceinline__ void gather3(const unsigned* __restrict__ tl,
    float Uf0, float Vf0, float dU, float dV, int iexc,
    float& a0, float& a1)
{
    __half2 acc = __float2half2_rn(0.0f);
    #pragma unroll
    for (int k = 0; k < 3; ++k) {
        const float Uf = fmaf((float)k, dU, Uf0);   // independent, no chain
        const float Vf = fmaf((float)k, dV, Vf0);
        const float fU = floorf(Uf), fV = floorf(Vf);
        const float wU1 = Uf - fU;
        const float wV1 = Vf - fV;
        // fU*32+fV exact small ints; rel in [0, 768)
        const int rel = (int)fmaf(fU, (float)TSW, fV);
        const __half2 x00 = *(const __half2*)(tl + rel);
        const __half2 x01 = *(const __half2*)(tl + rel + 1);
        const __half2 x10 = *(const __half2*)(tl + rel + TSW);
        const __half2 x11 = *(const __half2*)(tl + rel + TSW + 1);
        const __half2 wv2 = __float2half2_rn(wV1);
        const __half2 wu2 = __float2half2_rn(wU1);
        const __half2 t0 = __hfma2(wv2, __hsub2(x01, x00), x00);
        const __half2 t1 = __hfma2(wv2, __hsub2(x11, x10), x10);
        __half2 v = __hfma2(wu2, __hsub2(t1, t0), t0);
        if (TAIL && k >= iexc) v = __float2half2_rn(0.0f);   // phantom i >= G
        acc = __hadd2(acc, v);
    }
    a0 += __low2float(acc);
    a1 += __high2float(acc);
}

// ------- main gather: wave-private double-buffered, counted vmcnt ----------
__global__ __launch_bounds__(256) void radon_wv2(
    const unsigned* __restrict__ xIh, const unsigned* __restrict__ xTIh,
    const int* __restrict__ theta, float* __restrict__ out)
{
    __shared__ unsigned tile[4 * 2 * TCELLS];   // 4 waves x 2 bufs x 3 KB
    __shared__ float red[4][2][16];

    const int blk  = blockIdx.x;           // 0..2159
    const int t    = blk / NJB;
    const int jb   = blk - t * NJB;
    const int tid  = threadIdx.x;
    const int lane = tid & 63;
    const int wid  = tid >> 6;             // 0..3
    const int wj   = wid & 1;              // j half (16)
    const int wi   = wid >> 1;             // i half
    const int jl   = lane & 15;            // j lane
    const int kk   = lane >> 4;            // i 3-group (0..3)

    unsigned* tileW = tile + wid * (2 * TCELLS);

    const float th = (float)theta[t] * DEG2RAD;
    const float c = cosf(th), s = sinf(th);
    const float s181 = s * 181.0f, c181 = c * 181.0f;

    const int caseA = (fabsf(c) >= fabsf(s));
    const unsigned* __restrict__ srcC = caseA ? xIh : xTIh;

    const float slopeU = caseA ? c181 : s181;
    const float slopeV = caseA ? s181 : c181;
    const float dU = slopeU * STEP;
    const float dV = slopeV * STEP;

    // per-lane sample base (U(i) = dU*i + U00L, padded-grid coords)
    const int   j  = jb * 32 + wj * 16 + jl;   // phantom j >= 363 ok
    const float xj = fmaf((float)j, STEP, -1.0f);
    const float bx = fmaf(c,  xj, 1.0f) * 181.0f;
    const float by = fmaf(-s, xj, 1.0f) * 181.0f;
    const float U00L = (caseA ? by : bx) - slopeU;
    const float V00L = (caseA ? bx : by) - slopeV;

    // wave-corner bases (identical fmaf chain, j endpoints of this wave)
    const int   j0  = jb * 32 + wj * 16;
    const float xjm = fmaf((float)j0,        STEP, -1.0f);
    const float xjM = fmaf((float)(j0 + 15), STEP, -1.0f);
    const float bxm = fmaf(c,  xjm, 1.0f) * 181.0f;
    const float bym = fmaf(-s, xjm, 1.0f) * 181.0f;
    const float bxM = fmaf(c,  xjM, 1.0f) * 181.0f;
    const float byM = fmaf(-s, xjM, 1.0f) * 181.0f;
    const float U00m = (caseA ? bym : bxm) - slopeU;
    const float U00M = (caseA ? byM : bxM) - slopeU;
    const float V00m = (caseA ? bxm : bym) - slopeV;
    const float V00M = (caseA ? bxM : byM) - slopeV;

    const float fiofs = (float)(kk * 3);
    const int   nsub  = wi ? 15 : 16;      // wi=1: sub 15 fully phantom
    const int   isub0 = wi * 16;

    // bbox of subtile `sub` (4 corners each axis; same chain as samples)
    auto bboxmins = [&](int sub, int& r0o, int& c0o) {
        const int i0 = (isub0 + sub) * 12;
        const float fi0 = (float)i0, fi1 = (float)(i0 + 11);
        const float Umin = fminf(fminf(fmaf(dU, fi0, U00m), fmaf(dU, fi0, U00M)),
                                 fminf(fmaf(dU, fi1, U00m), fmaf(dU, fi1, U00M)));
        const float Vmin = fminf(fminf(fmaf(dV, fi0, V00m), fmaf(dV, fi0, V00M)),
                                 fminf(fmaf(dV, fi1, V00m), fmaf(dV, fi1, V00M)));
        r0o = __builtin_amdgcn_readfirstlane((int)floorf(Umin) - 1);
        c0o = __builtin_amdgcn_readfirstlane((int)floorf(Vmin) - 1);
    };
    auto dostage = [&](int bufsel, int r0, int c0) {
        char* b = (char*)(tileW + bufsel * TCELLS);
        const int r0p = r0 - PADB, c0p = c0 - PADB;
        if (r0p >= -4 && r0p <= 236 && c0p >= -4 && c0p <= 228)
            stage24<true >(b, srcC, r0p, c0p, lane);
        else
            stage24<false>(b, srcC, r0p, c0p, lane);
    };

    float a0 = 0.f, a1 = 0.f;

    // ---- prologue: stage subtile 0 into buf 0 ----
    int r0c, c0c;                          // current subtile's bbox origin
    bboxmins(0, r0c, c0c);
    dostage(0, r0c, c0c);

    for (int sub = 0; sub < nsub; ++sub) {
        int r0n = 0, c0n = 0;
        const bool pf = (sub + 1) < nsub;
        if (pf) {
            bboxmins(sub + 1, r0n, c0n);
            // prior gather (sub-1) read buf[(sub+1)&1]; drain before overwrite
            asm volatile("s_waitcnt lgkmcnt(0)" ::: "memory");
            __builtin_amdgcn_sched_barrier(0);
            dostage((sub + 1) & 1, r0n, c0n);
            // counted wait: leave next's 3 loads in flight, drain current's
            asm volatile("s_waitcnt vmcnt(3)" ::: "memory");
        } else {
            asm volatile("s_waitcnt vmcnt(0)" ::: "memory");
        }
        __builtin_amdgcn_sched_barrier(0);

        // ---- gather 3 taps/lane from current buffer ----
        const unsigned* buf = tileW + (sub & 1) * TCELLS;
        const int i0 = (isub0 + sub) * 12;
        const float fi  = (float)i0 + fiofs;
        const float Uf0 = fmaf(dU, fi, U00L) - (float)r0c;
        const float Vf0 = fmaf(dV, fi, V00L) - (float)c0c;
        const int ibase = i0 + kk * 3;

        if (i0 + 11 < G) {
            gather3<false>(buf, Uf0, Vf0, dU, dV, 3, a0, a1);
        } else {
            gather3<true>(buf, Uf0, Vf0, dU, dV, G - ibase, a0, a1);
        }

        r0c = r0n; c0c = c0n;
    }

    // ---- reduce kk groups in-wave, wi halves across waves ----
    a0 += __shfl_xor(a0, 16); a1 += __shfl_xor(a1, 16);
    a0 += __shfl_xor(a0, 32); a1 += __shfl_xor(a1, 32);

    if (lane < 16) {
        red[wid][0][lane] = a0;
        red[wid][1][lane] = a1;
    }
    __syncthreads();

    if (tid < 64) {
        const int n = tid >> 5, jj = tid & 31;
        const int wj2 = jj >> 4, jl2 = jj & 15;
        const float v = red[wj2][n][jl2] + red[wj2 + 2][n][jl2];
        const int jo = jb * 32 + jj;
        if (jo < G)
            out[(n * G + jo) * NT + t] = v;
    }
}

extern "C" void kernel_launch(void* const* d_in, const int* in_sizes, int n_in,
                              void* d_out, int out_size, void* d_ws, size_t ws_size,
                              hipStream_t stream) {
    const float* x     = (const float*)d_in[0];
    const int*   theta = (const int*)d_in[1];
    float*       out   = (float*)d_out;

    const size_t XIH_OFF  = 0;
    const size_t XTIH_OFF = (size_t)CH * CW * 4;                 // 278,784
    const size_t NEED     = 2 * XTIH_OFF;                        // 557,568 B

    if (ws_size < NEED) {   // fallback: known-good gather kernel
        hipLaunchKernelGGL(radon_fwd, dim3(NT * NJBF), dim3(64, 4), 0, stream,
                           x, theta, out);
        return;
    }

    unsigned* xIh  = (unsigned*)((char*)d_ws + XIH_OFF);
    unsigned* xTIh = (unsigned*)((char*)d_ws + XTIH_OFF);

    hipLaunchKernelGGL(prep_k, dim3(81), dim3(32, 8), 0, stream,
                       x, xIh, xTIh);
    hipLaunchKernelGGL(radon_wv2, dim3(NT * NJB), dim3(256), 0, stream,
                       xIh, xTIh, theta, out);
}